// Round 1
// baseline (160.739 us; speedup 1.0000x reference)
//
#include <hip/hip_runtime.h>
#include <cstdint>

#define NEMB   512     // codebook entries
#define DQ     64      // quantized vector dim (in_mem*out_mem)
#define NROWS  4096    // in_g*out_g weight rows
#define BATCH  8192
#define KDIM   512     // in_g*in_mem
#define NDIM   512     // out_g*out_mem

typedef __attribute__((ext_vector_type(8))) short bf16x8;
typedef __attribute__((ext_vector_type(4))) float floatx4;

__device__ __forceinline__ unsigned short f2bf(float f) {
    unsigned int u = __float_as_uint(f);
    u += 0x7fffu + ((u >> 16) & 1u);     // RNE
    return (unsigned short)(u >> 16);
}

__device__ __forceinline__ void async16(const void* g, void* l) {
    __builtin_amdgcn_global_load_lds(
        (const __attribute__((address_space(1))) void*)g,
        (__attribute__((address_space(3))) void*)l, 16, 0, 0);
}

// ---------------------------------------------------------------------------
// Kernel 1: x fp32 -> bf16; codebook column squared-norms in f64; zero diff slot
// ---------------------------------------------------------------------------
__global__ __launch_bounds__(256) void prep_kernel(
    const float* __restrict__ x,        // [8192*512]
    const float* __restrict__ embed,    // [64][512]
    unsigned short* __restrict__ xb,    // bf16 out [8192*512]
    double* __restrict__ e2,            // [512]
    float* diff_slot)
{
    const int gid = blockIdx.x * 256 + threadIdx.x;   // 524288 threads
#pragma unroll
    for (int it = 0; it < 2; ++it) {
        const int idx = gid + it * 524288;            // float4 index < 1048576
        float4 v = reinterpret_cast<const float4*>(x)[idx];
        ushort4 o;
        o.x = f2bf(v.x); o.y = f2bf(v.y); o.z = f2bf(v.z); o.w = f2bf(v.w);
        reinterpret_cast<ushort4*>(xb)[idx] = o;
    }
    if (gid < NEMB) {
        double s = 0.0;
        for (int d = 0; d < DQ; ++d) {
            double e = (double)embed[d * NEMB + gid];
            s = fma(e, e, s);
        }
        e2[gid] = s;
    }
    if (gid == 0 && diff_slot) *diff_slot = 0.f;
}

// ---------------------------------------------------------------------------
// Kernel 2: VQ argmin (f64 dists) + build W^T bf16 [NDIM][KDIM] + diff
// Block = 256 threads handles 16 weight rows; 16 threads/row scan 512 cands.
// ---------------------------------------------------------------------------
__global__ __launch_bounds__(256) void vq_kernel(
    const float* __restrict__ weight,   // [4096][64]
    const float* __restrict__ embed,    // [64][512]
    const double* __restrict__ e2,      // [512]
    unsigned short* __restrict__ wt,    // bf16 W^T [512][512]  (wt[n][k])
    float* diff_out,
    const int* __restrict__ use_qw)
{
    const int t = threadIdx.x;
    const int sub = t & 15;             // candidate slice within row
    const int rloc = t >> 4;            // 0..15 row within block
    const int row = blockIdx.x * 16 + rloc;
    const int g = row >> 6, og = row & 63;
    const bool qon = (use_qw[0] != 0);

    __shared__ float wlds[16 * 64];
    reinterpret_cast<float4*>(wlds)[t] =
        reinterpret_cast<const float4*>(weight + (size_t)blockIdx.x * 16 * 64)[t];
    __syncthreads();

    const float* wr = wlds + rloc * 64;
    double best = 1e300;
    int bidx = 0;
    if (qon) {
        for (int c = 0; c < 8; ++c) {
            const int j = c * 64 + sub * 4;   // ascending j within thread
            double d0 = 0, d1 = 0, d2 = 0, d3 = 0;
            for (int d = 0; d < DQ; ++d) {
                const double wv = (double)wr[d];
                const float4 e = *reinterpret_cast<const float4*>(embed + d * NEMB + j);
                d0 = fma(wv, (double)e.x, d0);
                d1 = fma(wv, (double)e.y, d1);
                d2 = fma(wv, (double)e.z, d2);
                d3 = fma(wv, (double)e.w, d3);
            }
            const double q0 = e2[j + 0] - 2.0 * d0;
            const double q1 = e2[j + 1] - 2.0 * d1;
            const double q2 = e2[j + 2] - 2.0 * d2;
            const double q3 = e2[j + 3] - 2.0 * d3;
            if (q0 < best) { best = q0; bidx = j + 0; }
            if (q1 < best) { best = q1; bidx = j + 1; }
            if (q2 < best) { best = q2; bidx = j + 2; }
            if (q3 < best) { best = q3; bidx = j + 3; }
        }
        // reduce (min dist, min index on tie) across the 16 lanes of this row
#pragma unroll
        for (int off = 1; off < 16; off <<= 1) {
            double ob = __shfl_xor(best, off, 64);
            int    oi = __shfl_xor(bidx, off, 64);
            if (ob < best || (ob == best && oi < bidx)) { best = ob; bidx = oi; }
        }
    }

    // write quantized row into W^T; accumulate diff
    float dsum = 0.f;
#pragma unroll
    for (int z = 0; z < 4; ++z) {
        const int d = sub * 4 + z;          // 0..63 within row
        const float wv = wr[d];
        float qv;
        if (qon) {
            qv = embed[d * NEMB + bidx];
            const float df = qv - wv;
            dsum = fmaf(df, df, dsum);
        } else {
            qv = wv;
        }
        const int i = d >> 3, om = d & 7;
        // W[k = g*8+i][n = og*8+om]  ->  wt[n*KDIM + k]
        wt[(size_t)(og * 8 + om) * KDIM + (g * 8 + i)] = f2bf(qv);
    }

    // block reduce dsum -> one atomic per block
#pragma unroll
    for (int off = 32; off > 0; off >>= 1) dsum += __shfl_down(dsum, off, 64);
    __shared__ float red[4];
    const int wave = t >> 6, lane = t & 63;
    if (lane == 0) red[wave] = dsum;
    __syncthreads();
    if (t == 0 && qon && diff_out)
        atomicAdd(diff_out, (red[0] + red[1] + red[2] + red[3]) * (1.f / (NROWS * DQ)));
}

// ---------------------------------------------------------------------------
// Kernel 3: res = xb[8192,512] @ wt^T   (wt stored [N][K] = B-transposed)
// m97 structure: 128x128 tile, BK=32, 4 waves, 16x16x32 bf16 MFMA,
// global_load_lds width 16.
// ---------------------------------------------------------------------------
__global__ __launch_bounds__(256) void gemm_kernel(
    const unsigned short* __restrict__ xb,   // bf16 [8192][512]
    const unsigned short* __restrict__ wt,   // bf16 [512][512]
    float* __restrict__ out)                 // fp32 [8192][512]
{
    __shared__ unsigned short As[128 * 32];  // [m][k] 8 KB
    __shared__ unsigned short Bs[128 * 32];  // [n][k] 8 KB

    const int tid  = threadIdx.x;
    const int wave = tid >> 6;
    const int lane = tid & 63;
    const int m0 = blockIdx.y * 128;
    const int n0 = blockIdx.x * 128;
    const int wm = (wave >> 1) * 64;
    const int wn = (wave & 1) * 64;

    const int srow = lane >> 2;          // staging row within 16-row chunk
    const int scol = (lane & 3) * 8;     // staging k offset (elements)
    const int mrow = lane & 15;          // fragment row
    const int koff = (lane >> 4) * 8;    // fragment k offset

    floatx4 acc[4][4] = {};

    for (int k0 = 0; k0 < KDIM; k0 += 32) {
        __syncthreads();
#pragma unroll
        for (int c = 0; c < 2; ++c) {
            const int q = wave * 2 + c;          // 16-row chunk id 0..7
            const int row = q * 16 + srow;
            async16(xb + (size_t)(m0 + row) * KDIM + k0 + scol, (char*)As + q * 1024);
            async16(wt + (size_t)(n0 + row) * KDIM + k0 + scol, (char*)Bs + q * 1024);
        }
        __syncthreads();

        bf16x8 a[4], b[4];
#pragma unroll
        for (int i = 0; i < 4; ++i)
            a[i] = *reinterpret_cast<const bf16x8*>(&As[(wm + i * 16 + mrow) * 32 + koff]);
#pragma unroll
        for (int j = 0; j < 4; ++j)
            b[j] = *reinterpret_cast<const bf16x8*>(&Bs[(wn + j * 16 + mrow) * 32 + koff]);
#pragma unroll
        for (int i = 0; i < 4; ++i)
#pragma unroll
            for (int j = 0; j < 4; ++j)
                acc[i][j] = __builtin_amdgcn_mfma_f32_16x16x32_bf16(a[i], b[j], acc[i][j], 0, 0, 0);
    }

    // C/D layout: col = lane&15, row = (lane>>4)*4 + reg  (m89-verified)
    const int col = lane & 15;
    const int rbase = (lane >> 4) * 4;
#pragma unroll
    for (int i = 0; i < 4; ++i)
#pragma unroll
        for (int j = 0; j < 4; ++j)
#pragma unroll
            for (int r = 0; r < 4; ++r) {
                const int mm = m0 + wm + i * 16 + rbase + r;
                const int nn = n0 + wn + j * 16 + col;
                out[(size_t)mm * NDIM + nn] = acc[i][j][r];
            }
}

// ---------------------------------------------------------------------------
extern "C" void kernel_launch(void* const* d_in, const int* in_sizes, int n_in,
                              void* d_out, int out_size, void* d_ws, size_t ws_size,
                              hipStream_t stream)
{
    const float* x      = (const float*)d_in[0];
    const float* weight = (const float*)d_in[1];
    const float* embed  = (const float*)d_in[2];
    const int*   use_qw = (const int*)d_in[3];
    float* out = (float*)d_out;

    // workspace layout: [0,512K) W^T bf16 ; [512K,516K) e2 f64 ; [1M,9M) x bf16
    unsigned short* wt = (unsigned short*)d_ws;
    double* e2         = (double*)((char*)d_ws + (512u << 10));
    unsigned short* xb = (unsigned short*)((char*)d_ws + (1u << 20));

    float* diff_slot = (out_size > BATCH * NDIM) ? (out + (size_t)BATCH * NDIM) : nullptr;

    prep_kernel<<<2048, 256, 0, stream>>>(x, embed, xb, e2, diff_slot);
    vq_kernel<<<NROWS / 16, 256, 0, stream>>>(weight, embed, e2, wt, diff_slot, use_qw);
    gemm_kernel<<<dim3(NDIM / 128, BATCH / 128), 256, 0, stream>>>(xb, wt, out);
}

// Round 2
// 113.323 us; speedup vs baseline: 1.4184x; 1.4184x over previous
//
#include <hip/hip_runtime.h>
#include <cstdint>

#define NEMB   512     // codebook entries
#define DQ     64      // quantized vector dim (in_mem*out_mem)
#define NROWS  4096    // in_g*out_g weight rows
#define BATCH  8192
#define KDIM   512     // in_g*in_mem
#define NDIM   512     // out_g*out_mem

typedef __attribute__((ext_vector_type(8))) short bf16x8;
typedef __attribute__((ext_vector_type(4))) float floatx4;

__device__ __forceinline__ unsigned short f2bf(float f) {
    unsigned int u = __float_as_uint(f);
    u += 0x7fffu + ((u >> 16) & 1u);     // RNE
    return (unsigned short)(u >> 16);
}

__device__ __forceinline__ void async16(const void* g, void* l) {
    __builtin_amdgcn_global_load_lds(
        (const __attribute__((address_space(1))) void*)g,
        (__attribute__((address_space(3))) void*)l, 16, 0, 0);
}

// ---------------------------------------------------------------------------
// Kernel 1: x fp32 -> bf16; codebook column squared-norms in f64; zero diff slot
// ---------------------------------------------------------------------------
__global__ __launch_bounds__(256) void prep_kernel(
    const float* __restrict__ x,        // [8192*512]
    const float* __restrict__ embed,    // [64][512]
    unsigned short* __restrict__ xb,    // bf16 out [8192*512]
    double* __restrict__ e2,            // [512]
    float* diff_slot)
{
    const int gid = blockIdx.x * 256 + threadIdx.x;   // 524288 threads
#pragma unroll
    for (int it = 0; it < 2; ++it) {
        const int idx = gid + it * 524288;            // float4 index < 1048576
        float4 v = reinterpret_cast<const float4*>(x)[idx];
        ushort4 o;
        o.x = f2bf(v.x); o.y = f2bf(v.y); o.z = f2bf(v.z); o.w = f2bf(v.w);
        reinterpret_cast<ushort4*>(xb)[idx] = o;
    }
    if (gid < NEMB) {
        double s = 0.0;
        for (int d = 0; d < DQ; ++d) {
            double e = (double)embed[d * NEMB + gid];
            s = fma(e, e, s);
        }
        e2[gid] = s;
    }
    if (gid == 0 && diff_slot) *diff_slot = 0.f;
}

// ---------------------------------------------------------------------------
// Kernel 2: VQ argmin (f64 dists, ILP-restructured) + W^T bf16 + diff
// Block = 256 threads = 16 rows. Wave w owns 4 rows; each lane scans 8
// contiguous candidates (j0 = lane*8) for all 4 rows -> 32 independent
// f64 FMA chains per thread (latency hidden by ILP at 1 wave/SIMD).
// ---------------------------------------------------------------------------
__global__ __launch_bounds__(256) void vq_kernel(
    const float* __restrict__ weight,   // [4096][64]
    const float* __restrict__ embed,    // [64][512]
    const double* __restrict__ e2,      // [512]
    unsigned short* __restrict__ wt,    // bf16 W^T [512][512]  (wt[n][k])
    float* diff_out,
    const int* __restrict__ use_qw)
{
    const int t    = threadIdx.x;
    const int wave = t >> 6;
    const int lane = t & 63;
    const int rblk = blockIdx.x * 16;    // first row of this block
    const bool qon = (use_qw[0] != 0);

    __shared__ float wlds[16 * 64];      // 4 KB: the block's 16 weight rows
    __shared__ int   bidx_lds[16];

    reinterpret_cast<float4*>(wlds)[t] =
        reinterpret_cast<const float4*>(weight + (size_t)rblk * 64)[t];
    __syncthreads();

    if (qon) {
        const int j0 = lane * 8;         // 8 contiguous candidates
        const int rw = wave * 4;         // wave's first local row

        double acc[4][8];
#pragma unroll
        for (int r = 0; r < 4; ++r)
#pragma unroll
            for (int c = 0; c < 8; ++c) acc[r][c] = 0.0;

        for (int d = 0; d < DQ; ++d) {
            const float4 ea = *reinterpret_cast<const float4*>(embed + d * NEMB + j0);
            const float4 eb = *reinterpret_cast<const float4*>(embed + d * NEMB + j0 + 4);
            double ev[8];
            ev[0] = (double)ea.x; ev[1] = (double)ea.y; ev[2] = (double)ea.z; ev[3] = (double)ea.w;
            ev[4] = (double)eb.x; ev[5] = (double)eb.y; ev[6] = (double)eb.z; ev[7] = (double)eb.w;
#pragma unroll
            for (int r = 0; r < 4; ++r) {
                const double wv = (double)wlds[(rw + r) * 64 + d];   // LDS broadcast
#pragma unroll
                for (int c = 0; c < 8; ++c)
                    acc[r][c] = fma(wv, ev[c], acc[r][c]);
            }
        }

        double e2v[8];
#pragma unroll
        for (int c = 0; c < 8; ++c) e2v[c] = e2[j0 + c];

#pragma unroll
        for (int r = 0; r < 4; ++r) {
            double best = 1e300;
            int bi = 0;
#pragma unroll
            for (int c = 0; c < 8; ++c) {
                const double q = fma(-2.0, acc[r][c], e2v[c]);
                if (q < best) { best = q; bi = j0 + c; }   // ascending j: strict < keeps lowest idx
            }
#pragma unroll
            for (int off = 1; off < 64; off <<= 1) {
                const double ob = __shfl_xor(best, off, 64);
                const int    oi = __shfl_xor(bi,   off, 64);
                if (ob < best || (ob == best && oi < bi)) { best = ob; bi = oi; }
            }
            if (lane == 0) bidx_lds[rw + r] = bi;
        }
    }
    __syncthreads();

    // ---- write phase: quantized row -> W^T bf16; accumulate diff ----
    const int sub  = t & 15;             // 4 dims per thread
    const int rloc = t >> 4;             // local row 0..15
    const int row  = rblk + rloc;
    const int g = row >> 6, og = row & 63;
    const int bidx = qon ? bidx_lds[rloc] : 0;
    const float* wr = wlds + rloc * 64;

    float dsum = 0.f;
#pragma unroll
    for (int z = 0; z < 4; ++z) {
        const int d = sub * 4 + z;       // 0..63 within row
        const float wv = wr[d];
        float qv;
        if (qon) {
            qv = embed[d * NEMB + bidx];
            const float df = qv - wv;
            dsum = fmaf(df, df, dsum);
        } else {
            qv = wv;
        }
        const int i = d >> 3, om = d & 7;
        // W[k = g*8+i][n = og*8+om]  ->  wt[n*KDIM + k]
        wt[(size_t)(og * 8 + om) * KDIM + (g * 8 + i)] = f2bf(qv);
    }

#pragma unroll
    for (int off = 32; off > 0; off >>= 1) dsum += __shfl_down(dsum, off, 64);
    __shared__ float red[4];
    if (lane == 0) red[wave] = dsum;
    __syncthreads();
    if (t == 0 && qon && diff_out)
        atomicAdd(diff_out, (red[0] + red[1] + red[2] + red[3]) * (1.f / (NROWS * DQ)));
}

// ---------------------------------------------------------------------------
// Kernel 3: res = xb[8192,512] @ wt^T   (wt stored [N][K] = B-transposed)
// 128x64 tile (A 128 rows, B 64 cols), BK=32, 4 waves in 2x2, 16x16x32 MFMA.
// grid = 8 x 64 = 512 blocks = 2 blocks/CU -> overlapped barrier drains.
// ---------------------------------------------------------------------------
__global__ __launch_bounds__(256) void gemm_kernel(
    const unsigned short* __restrict__ xb,   // bf16 [8192][512]
    const unsigned short* __restrict__ wt,   // bf16 [512][512]
    float* __restrict__ out)                 // fp32 [8192][512]
{
    __shared__ unsigned short As[128 * 32];  // [m][k] 8 KB
    __shared__ unsigned short Bs[64 * 32];   // [n][k] 4 KB

    const int tid  = threadIdx.x;
    const int wave = tid >> 6;
    const int lane = tid & 63;
    const int m0 = blockIdx.y * 128;
    const int n0 = blockIdx.x * 64;
    const int wm = (wave >> 1) * 64;         // wave m-offset (0/64)
    const int wn = (wave & 1) * 32;          // wave n-offset (0/32)

    const int srow = lane >> 2;              // staging row within 16-row chunk
    const int scol = (lane & 3) * 8;         // staging k offset (elements)
    const int mrow = lane & 15;              // fragment row
    const int koff = (lane >> 4) * 8;        // fragment k offset

    floatx4 acc[4][2] = {};

    for (int k0 = 0; k0 < KDIM; k0 += 32) {
        __syncthreads();
#pragma unroll
        for (int c = 0; c < 2; ++c) {
            const int q = wave * 2 + c;      // A chunk 0..7 (16 rows each)
            const int row = q * 16 + srow;
            async16(xb + (size_t)(m0 + row) * KDIM + k0 + scol, (char*)As + q * 1024);
        }
        {
            const int row = wave * 16 + srow;   // B chunk = wave (64 rows total)
            async16(wt + (size_t)(n0 + row) * KDIM + k0 + scol, (char*)Bs + wave * 1024);
        }
        __syncthreads();

        bf16x8 a[4], b[2];
#pragma unroll
        for (int i = 0; i < 4; ++i)
            a[i] = *reinterpret_cast<const bf16x8*>(&As[(wm + i * 16 + mrow) * 32 + koff]);
#pragma unroll
        for (int j = 0; j < 2; ++j)
            b[j] = *reinterpret_cast<const bf16x8*>(&Bs[(wn + j * 16 + mrow) * 32 + koff]);
#pragma unroll
        for (int i = 0; i < 4; ++i)
#pragma unroll
            for (int j = 0; j < 2; ++j)
                acc[i][j] = __builtin_amdgcn_mfma_f32_16x16x32_bf16(a[i], b[j], acc[i][j], 0, 0, 0);
    }

    // C/D layout: col = lane&15, row = (lane>>4)*4 + reg  (m89-verified)
    const int col = lane & 15;
    const int rbase = (lane >> 4) * 4;
#pragma unroll
    for (int i = 0; i < 4; ++i)
#pragma unroll
        for (int j = 0; j < 2; ++j)
#pragma unroll
            for (int r = 0; r < 4; ++r) {
                const int mm = m0 + wm + i * 16 + rbase + r;
                const int nn = n0 + wn + j * 16 + col;
                out[(size_t)mm * NDIM + nn] = acc[i][j][r];
            }
}

// ---------------------------------------------------------------------------
extern "C" void kernel_launch(void* const* d_in, const int* in_sizes, int n_in,
                              void* d_out, int out_size, void* d_ws, size_t ws_size,
                              hipStream_t stream)
{
    const float* x      = (const float*)d_in[0];
    const float* weight = (const float*)d_in[1];
    const float* embed  = (const float*)d_in[2];
    const int*   use_qw = (const int*)d_in[3];
    float* out = (float*)d_out;

    // workspace layout: [0,512K) W^T bf16 ; [512K,516K) e2 f64 ; [1M,9M) x bf16
    unsigned short* wt = (unsigned short*)d_ws;
    double* e2         = (double*)((char*)d_ws + (512u << 10));
    unsigned short* xb = (unsigned short*)((char*)d_ws + (1u << 20));

    float* diff_slot = (out_size > BATCH * NDIM) ? (out + (size_t)BATCH * NDIM) : nullptr;

    prep_kernel<<<2048, 256, 0, stream>>>(x, embed, xb, e2, diff_slot);
    vq_kernel<<<NROWS / 16, 256, 0, stream>>>(weight, embed, e2, wt, diff_slot, use_qw);
    gemm_kernel<<<dim3(NDIM / 64, BATCH / 128), 256, 0, stream>>>(xb, wt, out);
}